// Round 8
// baseline (306.287 us; speedup 1.0000x reference)
//
// GroupedSubMConv3d v6 — v5 core + reg-prefetched nb (T14 split) + TPB=25 + cached cvt reads
#include <hip/hip_runtime.h>
#include <hip/hip_fp16.h>

#define NVOX 400000
#define KVOL 27
#define CTOT 64
#define NTILES (NVOX / 16)     // 25000 exact
#define NPAIR 14               // 27 offsets -> 14 pairs (last half-padded)
#define TPB 25                 // tiles per persistent block
#define NBLOCKS (NTILES / TPB) // 1000 exact
#define NBW (16 * KVOL)        // 432 nb dwords per tile
#define WFRAG_HALVES (4 * NPAIR * 64 * 8)     // 28672 f16 = 57344 B
#define FEAT_BLOCKS (NVOX * CTOT / 8 / 256)   // 12500 exact
#define W_BLOCKS (WFRAG_HALVES / 256)         // 112 exact

// ---------------- ws layout ----------------
// featH : _Float16[NVOX*64]   offset 0           (51,200,000 B)
// wfrag : _Float16[28672]     offset 51,200,000  (57,344 B)
#define FEATH_OFF 0
#define WFRAG_OFF 51200000

typedef __attribute__((ext_vector_type(8))) _Float16 half8;
typedef __attribute__((ext_vector_type(4))) float float4v;

// Fused convert kernel. CACHED reads: features/weight were just rewritten by
// the harness reset -> L2/L3-resident; NT reads would force the slow path.
__global__ void cvt_fused_kernel(const float* __restrict__ f,
                                 const float* __restrict__ w,
                                 _Float16* __restrict__ fh,
                                 _Float16* __restrict__ wf) {
    const int b = blockIdx.x;
    if (b < FEAT_BLOCKS) {
        const int t = b * 256 + threadIdx.x;     // < 3,200,000
        const float4v* fp = (const float4v*)f + (size_t)t * 2;
        float4v a = fp[0];
        float4v c = fp[1];
        union { _Float16 h[8]; uint4 u; } r;
        r.h[0] = (_Float16)a[0]; r.h[1] = (_Float16)a[1];
        r.h[2] = (_Float16)a[2]; r.h[3] = (_Float16)a[3];
        r.h[4] = (_Float16)c[0]; r.h[5] = (_Float16)c[1];
        r.h[6] = (_Float16)c[2]; r.h[7] = (_Float16)c[3];
        ((uint4*)fh)[t] = r.u;
    } else {
        // weight[g][ko][ci][co] fp32 -> B-frag f16:
        // wf[g][p][lane][j] = w[g][2p+(quad>>1)][ci=(quad&1)*8+j][co=lane&15]
        // ko >= 27 (pair-13 second slot) -> 0.0
        const int t = (b - FEAT_BLOCKS) * 256 + threadIdx.x;
        if (t < WFRAG_HALVES) {
            int j = t & 7;
            int l = (t >> 3) & 63;
            int gp = t >> 9;            // 0..55
            int p = gp % NPAIR;
            int g = gp / NPAIR;
            int co = l & 15;
            int quad = l >> 4;
            int ko = 2 * p + (quad >> 1);
            int ci = (quad & 1) * 8 + j;
            float val = (ko < KVOL) ? w[((g * KVOL + ko) * 16 + ci) * 16 + co] : 0.f;
            wf[t] = (_Float16)val;
        }
    }
}

__global__ __launch_bounds__(256) void conv_main_kernel(
        const _Float16* __restrict__ fh,
        const uint4*    __restrict__ wfrag,
        const float*    __restrict__ bias,
        const int*      __restrict__ nb,
        float* __restrict__ out) {
    __shared__ int s_nb[NBW];            // linear [432]
    const int t = threadIdx.x;
    const int lane = t & 63;
    const int g = t >> 6;                // wave index = group
    const int v = lane & 15;             // voxel within tile (A-frag row m)
    const int quad = lane >> 4;
    const int q2 = quad >> 1;            // which offset of the pair
    const int half = quad & 1;           // which 8-ci half
    const int co = lane & 15;
    const int vb = v * KVOL;

    // bijective XCD swizzle: NBLOCKS=1000 -> q=125, r=0 (exact)
    const int wgid = (blockIdx.x & 7) * (NBLOCKS / 8) + (blockIdx.x >> 3);
    const int tile0 = wgid * TPB;

    // B-fragments resident in registers, loaded ONCE per block (amortized 25x)
    uint4 wB[NPAIR];
#pragma unroll
    for (int p = 0; p < NPAIR; ++p)
        wB[p] = wfrag[(g * NPAIR + p) * 64 + lane];

    const _Float16* fbase = fh + g * 16 + half * 8;
    const float breg = bias[g * 16 + co];

    // ---- nb register prefetch (T14 issue-early / write-late) ----
    // thread t covers dwords t and t+256 (t+256 valid only for t<176)
    const bool two = (t < NBW - 256);
    const int* src0 = nb + (size_t)tile0 * NBW;
    int r0 = __builtin_nontemporal_load(src0 + t);
    int r1 = two ? __builtin_nontemporal_load(src0 + t + 256) : -1;

    for (int tt = 0; tt < TPB; ++tt) {
        // prev tile's s_nb readers are done (barrier at end of prev iter)
        s_nb[t] = r0;
        if (two) s_nb[t + 256] = r1;
        __syncthreads();

        // all 14 pair-indices up front (stride 27: <=2-way bank alias, free)
        int ix[NPAIR];
#pragma unroll
        for (int p = 0; p < NPAIR - 1; ++p)
            ix[p] = s_nb[vb + 2 * p + q2];
        ix[NPAIR - 1] = (q2 == 0) ? s_nb[vb + 26] : -1;

        // exec-masked gathers: inactive lanes issue/return nothing
        uint4 a[NPAIR];
#pragma unroll
        for (int p = 0; p < NPAIR; ++p) {
            uint4 z = {0u, 0u, 0u, 0u};
            a[p] = z;
            if (ix[p] >= 0)
                a[p] = *(const uint4*)(fbase + (size_t)ix[p] * CTOT);
        }

        // issue NEXT tile's nb loads now: latency hides under MFMA + stores
        if (tt + 1 < TPB) {
            const int* srcn = nb + (size_t)(tile0 + tt + 1) * NBW;
            r0 = __builtin_nontemporal_load(srcn + t);
            if (two) r1 = __builtin_nontemporal_load(srcn + t + 256);
        }
        // pin: gathers + nb prefetch issued before the MFMA cluster
        __builtin_amdgcn_sched_barrier(0);

        // two independent accumulator chains
        float4v acc0 = {0.f, 0.f, 0.f, 0.f};
        float4v acc1 = {0.f, 0.f, 0.f, 0.f};
#pragma unroll
        for (int p = 0; p < NPAIR; p += 2) {
            acc0 = __builtin_amdgcn_mfma_f32_16x16x32_f16(
                __builtin_bit_cast(half8, a[p]),
                __builtin_bit_cast(half8, wB[p]), acc0, 0, 0, 0);
            acc1 = __builtin_amdgcn_mfma_f32_16x16x32_f16(
                __builtin_bit_cast(half8, a[p + 1]),
                __builtin_bit_cast(half8, wB[p + 1]), acc1, 0, 0, 0);
        }

        // C/D layout: col(co)=lane&15, row(voxel)=quad*4+r; NT stores
        float* ob = out + ((size_t)((tile0 + tt) * 16 + quad * 4)) * CTOT + g * 16 + co;
#pragma unroll
        for (int r = 0; r < 4; ++r)
            __builtin_nontemporal_store(acc0[r] + acc1[r] + breg, ob + (size_t)r * CTOT);

        // protect s_nb for next iteration's write (readers above are done)
        __syncthreads();
    }
}

extern "C" void kernel_launch(void* const* d_in, const int* in_sizes, int n_in,
                              void* d_out, int out_size, void* d_ws, size_t ws_size,
                              hipStream_t stream) {
    const float* features = (const float*)d_in[0];
    const float* weight   = (const float*)d_in[1];
    const float* bias     = (const float*)d_in[2];
    const int*   nb       = (const int*)d_in[3];
    float* out = (float*)d_out;

    char* ws = (char*)d_ws;
    _Float16* featH = (_Float16*)(ws + FEATH_OFF);
    _Float16* wf    = (_Float16*)(ws + WFRAG_OFF);

    cvt_fused_kernel<<<FEAT_BLOCKS + W_BLOCKS, 256, 0, stream>>>(features, weight, featH, wf);
    conv_main_kernel<<<NBLOCKS, 256, 0, stream>>>(featH, (const uint4*)wf, bias, nb, out);
}